// Round 2
// baseline (186.182 us; speedup 1.0000x reference)
//
#include <hip/hip_runtime.h>

#define BN_EPS 1e-5f

typedef _Float16 half8 __attribute__((ext_vector_type(8)));
typedef float f32x4 __attribute__((ext_vector_type(4)));

__device__ __forceinline__ float tanh_fast(float x){
  float e = __expf(2.0f * x);
  return 1.0f - 2.0f / (e + 1.0f);
}

// ---------------- prep: W1 -> fp16 copy (row-major [e][d]), BN scale/shift ----------------
__global__ __launch_bounds__(256) void k_prep(const float* __restrict__ W1,
    const float* __restrict__ gamma, const float* __restrict__ beta,
    const float* __restrict__ rmean, const float* __restrict__ rvar,
    _Float16* __restrict__ Bp, float* __restrict__ bns, float* __restrict__ bnb){
  int i = blockIdx.x * 256 + threadIdx.x;   // grid=256 -> 65536 = 256*256
  Bp[i] = (_Float16)W1[i];
  if (i < 4096){
    float sc = gamma[i] * rsqrtf(rvar[i] + BN_EPS);
    bns[i] = sc;
    bnb[i] = beta[i] - rmean[i] * sc;
  }
}

// ---------------- fused GEMM + BN + tanh + dot(x_h) -> a_t ----------------
// block: 512 thr (8 waves), tile BM=128 s-rows x BN=256 e-cols, K=256, BK=64 (4 steps).
// wave (wm=w>>2, wn=w&3) owns 64 rows x 64 cols. B (fp16 W1) register-direct from L2.
// A: f32 global -> cvt f16 -> LDS double buffer, padded stride 72 halves (2-way banks).
__global__ __launch_bounds__(512) void k_at(const float* __restrict__ xh,
    const float* __restrict__ xhpre, const _Float16* __restrict__ Bp,
    const float* __restrict__ bns, const float* __restrict__ bnb,
    float* __restrict__ a_t){
  constexpr int S = 4096, Dd = 256;
  constexpr int LDA = 72;   // halves; 144B stride = 36 banks -> 2-way (free)
  const int bid = blockIdx.x;
  const int b  = bid >> 5;
  const int s0 = (bid & 31) * 128;
  const int tid = threadIdx.x;
  const int lane = tid & 63;
  const int w = tid >> 6;
  const int wm = w >> 2, wn = w & 3;
  const int kg = lane >> 4;      // k-group 0..3
  const int lr = lane & 15;

  __shared__ _Float16 A[2][128 * LDA];
  __shared__ float bnsc[128], bnsh[128];
  __shared__ float red[4][128];

  if (tid < 128){ bnsc[tid] = bns[s0 + tid]; bnsh[tid] = bnb[s0 + tid]; }

  float xhv[4];
  #pragma unroll
  for (int nt = 0; nt < 4; ++nt) xhv[nt] = xh[b * 256 + wn * 64 + nt * 16 + lr];

  const float* Abase = xhpre + ((size_t)b * S + s0) * Dd;
  const int srow = tid >> 2;            // 0..127
  const int skq  = (tid & 3) * 16;      // 0,16,32,48 (floats)
  const float* srcb = Abase + (size_t)srow * Dd + skq;

  // ---- prologue: stage step 0 ----
  {
    const float4* sp = reinterpret_cast<const float4*>(srcb);
    float4 v0 = sp[0], v1 = sp[1], v2 = sp[2], v3 = sp[3];
    union { _Float16 h[16]; uint4 u[2]; } pk;
    pk.h[0]=(_Float16)v0.x; pk.h[1]=(_Float16)v0.y; pk.h[2]=(_Float16)v0.z; pk.h[3]=(_Float16)v0.w;
    pk.h[4]=(_Float16)v1.x; pk.h[5]=(_Float16)v1.y; pk.h[6]=(_Float16)v1.z; pk.h[7]=(_Float16)v1.w;
    pk.h[8]=(_Float16)v2.x; pk.h[9]=(_Float16)v2.y; pk.h[10]=(_Float16)v2.z; pk.h[11]=(_Float16)v2.w;
    pk.h[12]=(_Float16)v3.x; pk.h[13]=(_Float16)v3.y; pk.h[14]=(_Float16)v3.z; pk.h[15]=(_Float16)v3.w;
    _Float16* dst = &A[0][0] + srow * LDA + skq;
    *reinterpret_cast<uint4*>(dst) = pk.u[0];
    *reinterpret_cast<uint4*>(dst + 8) = pk.u[1];
  }
  __syncthreads();

  f32x4 acc[4][4] = {};
  const _Float16* brow = Bp + (size_t)(wn * 64 + lr) * 256 + kg * 8;

  #pragma unroll
  for (int k0 = 0; k0 < 4; ++k0){
    // issue next-step A loads early (hide HBM latency under MFMA)
    float4 n0, n1, n2, n3;
    if (k0 < 3){
      const float4* sp = reinterpret_cast<const float4*>(srcb + (k0 + 1) * 64);
      n0 = sp[0]; n1 = sp[1]; n2 = sp[2]; n3 = sp[3];
    }

    const _Float16* Ar = &A[k0 & 1][0];
    #pragma unroll
    for (int kk = 0; kk < 2; ++kk){
      half8 afr[4], bfr[4];
      #pragma unroll
      for (int nt = 0; nt < 4; ++nt)
        bfr[nt] = *reinterpret_cast<const half8*>(brow + (size_t)nt * 16 * 256 + k0 * 64 + kk * 32);
      #pragma unroll
      for (int mt = 0; mt < 4; ++mt)
        afr[mt] = *reinterpret_cast<const half8*>(Ar + (wm * 64 + mt * 16 + lr) * LDA + kk * 32 + kg * 8);
      #pragma unroll
      for (int mt = 0; mt < 4; ++mt)
        #pragma unroll
        for (int nt = 0; nt < 4; ++nt)
          acc[mt][nt] = __builtin_amdgcn_mfma_f32_16x16x32_f16(afr[mt], bfr[nt], acc[mt][nt], 0, 0, 0);
    }

    if (k0 < 3){
      union { _Float16 h[16]; uint4 u[2]; } pk;
      pk.h[0]=(_Float16)n0.x; pk.h[1]=(_Float16)n0.y; pk.h[2]=(_Float16)n0.z; pk.h[3]=(_Float16)n0.w;
      pk.h[4]=(_Float16)n1.x; pk.h[5]=(_Float16)n1.y; pk.h[6]=(_Float16)n1.z; pk.h[7]=(_Float16)n1.w;
      pk.h[8]=(_Float16)n2.x; pk.h[9]=(_Float16)n2.y; pk.h[10]=(_Float16)n2.z; pk.h[11]=(_Float16)n2.w;
      pk.h[12]=(_Float16)n3.x; pk.h[13]=(_Float16)n3.y; pk.h[14]=(_Float16)n3.z; pk.h[15]=(_Float16)n3.w;
      _Float16* dst = &A[(k0 + 1) & 1][0] + srow * LDA + skq;
      *reinterpret_cast<uint4*>(dst) = pk.u[0];
      *reinterpret_cast<uint4*>(dst + 8) = pk.u[1];
    }
    __syncthreads();
  }

  // epilogue: BN + tanh + dot(x_h); reduce over 16 cols (lr) then 4 wn groups via LDS
  #pragma unroll
  for (int mt = 0; mt < 4; ++mt){
    #pragma unroll
    for (int r = 0; r < 4; ++r){
      int row = wm * 64 + mt * 16 + kg * 4 + r;   // C/D: col=lane&15, row=(lane>>4)*4+reg
      float sc = bnsc[row], sh = bnsh[row];
      float sum = 0.f;
      #pragma unroll
      for (int nt = 0; nt < 4; ++nt){
        float hv = fmaf(acc[mt][nt][r], sc, sh);
        sum = fmaf(tanh_fast(hv), xhv[nt], sum);
      }
      sum += __shfl_xor(sum, 1);
      sum += __shfl_xor(sum, 2);
      sum += __shfl_xor(sum, 4);
      sum += __shfl_xor(sum, 8);
      if (lr == 0) red[wn][row] = sum;
    }
  }
  __syncthreads();
  if (tid < 128){
    float v = red[0][tid] + red[1][tid] + red[2][tid] + red[3][tid];
    a_t[(size_t)b * S + s0 + tid] = v;
  }
}

// ---------------- softmax over s (4096) per b ----------------
__global__ __launch_bounds__(256) void k_softmax(const float* __restrict__ at, float* __restrict__ as_){
  int b = blockIdx.x, tid = threadIdx.x;
  int w = tid >> 6, lane = tid & 63;
  __shared__ float rm[4], rz[4];
  float v[16];
  float m = -1e30f;
  #pragma unroll
  for (int i = 0; i < 16; ++i){ v[i] = at[(size_t)b * 4096 + i * 256 + tid]; m = fmaxf(m, v[i]); }
  #pragma unroll
  for (int o = 1; o < 64; o <<= 1) m = fmaxf(m, __shfl_xor(m, o));
  if (lane == 0) rm[w] = m;
  __syncthreads();
  m = fmaxf(fmaxf(rm[0], rm[1]), fmaxf(rm[2], rm[3]));
  float e[16], z = 0.f;
  #pragma unroll
  for (int i = 0; i < 16; ++i){ e[i] = __expf(v[i] - m); z += e[i]; }
  #pragma unroll
  for (int o = 1; o < 64; o <<= 1) z += __shfl_xor(z, o);
  if (lane == 0) rz[w] = z;
  __syncthreads();
  z = rz[0] + rz[1] + rz[2] + rz[3];
  float inv = 1.0f / z;
  #pragma unroll
  for (int i = 0; i < 16; ++i) as_[(size_t)b * 4096 + i * 256 + tid] = e[i] * inv;
}

// ---------------- partial weighted sums over 128-s chunks, float4 lanes ----------------
// block: (b, chunk c). wave w covers s in [c*128 + w*32, +32), lane -> d4 = lane*4.
__global__ __launch_bounds__(256) void k_wsum(const float* __restrict__ as_,
    const float* __restrict__ xp, float* __restrict__ partial){
  int bid = blockIdx.x;          // 64*32 = 2048
  int b = bid >> 5, c = bid & 31;
  int tid = threadIdx.x, w = tid >> 6, lane = tid & 63;
  __shared__ float av[128];
  __shared__ f32x4 red[4][64];
  if (tid < 128) av[tid] = as_[(size_t)b * 4096 + c * 128 + tid];
  __syncthreads();
  const float* x = xp + ((size_t)(b * 4096 + c * 128 + w * 32)) * 256 + lane * 4;
  f32x4 acc0 = {}, acc1 = {};
  #pragma unroll
  for (int s = 0; s < 32; s += 2){
    f32x4 v0 = *reinterpret_cast<const f32x4*>(x + (size_t)s * 256);
    f32x4 v1 = *reinterpret_cast<const f32x4*>(x + (size_t)(s + 1) * 256);
    float a0 = av[w * 32 + s], a1 = av[w * 32 + s + 1];
    acc0 += v0 * a0;
    acc1 += v1 * a1;
  }
  red[w][lane] = acc0 + acc1;
  __syncthreads();
  if (tid < 64){
    f32x4 r = red[0][tid] + red[1][tid] + red[2][tid] + red[3][tid];
    *reinterpret_cast<f32x4*>(partial + (size_t)bid * 256 + tid * 4) = r;
  }
}

// ---------------- final: out[b,d] = W2[d] * sum_c partial ----------------
__global__ __launch_bounds__(256) void k_out(const float* __restrict__ partial,
    const float* __restrict__ W2, float* __restrict__ out){
  int b = blockIdx.x, d = threadIdx.x;
  float s = 0.f;
  #pragma unroll
  for (int c = 0; c < 32; ++c) s += partial[(size_t)(b * 32 + c) * 256 + d];
  out[b * 256 + d] = s * W2[d];
}

extern "C" void kernel_launch(void* const* d_in, const int* in_sizes, int n_in,
                              void* d_out, int out_size, void* d_ws, size_t ws_size,
                              hipStream_t stream){
  const float* x_h    = (const float*)d_in[0];
  const float* x_hpre = (const float*)d_in[1];
  const float* W1     = (const float*)d_in[2];
  const float* W2     = (const float*)d_in[3];
  const float* gamma  = (const float*)d_in[4];
  const float* beta   = (const float*)d_in[5];
  const float* rmean  = (const float*)d_in[6];
  const float* rvar   = (const float*)d_in[7];
  float* out = (float*)d_out;

  char* ws = (char*)d_ws;
  _Float16* Bp = (_Float16*)(ws);           // 131072 B
  float* bns  = (float*)(ws + 131072);      // 16 KB
  float* bnb  = (float*)(ws + 147456);      // 16 KB
  float* at   = (float*)(ws + 163840);      // 1 MB
  float* as_  = (float*)(ws + 1212416);     // 1 MB
  float* part = (float*)(ws + 2260992);     // 2 MB  (total ~4.2 MB)

  hipLaunchKernelGGL(k_prep,    dim3(256),  dim3(256), 0, stream, W1, gamma, beta, rmean, rvar, Bp, bns, bnb);
  hipLaunchKernelGGL(k_at,      dim3(2048), dim3(512), 0, stream, x_h, x_hpre, Bp, bns, bnb, at);
  hipLaunchKernelGGL(k_softmax, dim3(64),   dim3(256), 0, stream, at, as_);
  hipLaunchKernelGGL(k_wsum,    dim3(2048), dim3(256), 0, stream, as_, x_hpre, part);
  hipLaunchKernelGGL(k_out,     dim3(64),   dim3(256), 0, stream, part, W2, out);
}

// Round 3
// 133.807 us; speedup vs baseline: 1.3914x; 1.3914x over previous
//
#include <hip/hip_runtime.h>

#define BN_EPS 1e-5f

typedef _Float16 half8 __attribute__((ext_vector_type(8)));
typedef float f32x4 __attribute__((ext_vector_type(4)));

__device__ __forceinline__ float tanh_fast(float x){
  float e = __expf(2.0f * x);
  return 1.0f - 2.0f / (e + 1.0f);
}

// ---------------- prep: W1 -> fp16 in MFMA-fragment order + BN scale/shift ----------------
// Fragment (q,c): q = k-chunk (32 k each, 0..7), c = col-block (16 e each, 0..15).
// Within fragment: lane l = kg*16+lr holds 8 halves: e = c*16+lr, d = q*32+kg*8+j.
// Bp2 halves-index = ((q*16 + c)*64 + l)*8 + j  -> k_at loads are 1KB/wave contiguous.
__global__ __launch_bounds__(256) void k_prep(const float* __restrict__ W1,
    const float* __restrict__ gamma, const float* __restrict__ beta,
    const float* __restrict__ rmean, const float* __restrict__ rvar,
    _Float16* __restrict__ Bp2, float* __restrict__ bns, float* __restrict__ bnb){
  int i = blockIdx.x * 256 + threadIdx.x;   // 0..65535
  int j  = i & 7;
  int l  = (i >> 3) & 63;
  int c  = (i >> 9) & 15;
  int q  = (i >> 13) & 7;
  int lr = l & 15, kg = l >> 4;
  int e  = c * 16 + lr;
  int d  = q * 32 + kg * 8 + j;
  Bp2[i] = (_Float16)W1[e * 256 + d];
  if (i < 4096){
    float sc = gamma[i] * rsqrtf(rvar[i] + BN_EPS);
    bns[i] = sc;
    bnb[i] = beta[i] - rmean[i] * sc;
  }
}

// ---------------- fused GEMM + BN + tanh + dot(x_h) -> a_t ----------------
// 512 thr (8 waves), BM=128 x BN=256, K=256, BK=64 (4 steps, 1 barrier each).
// wave (wm,wn) owns 64x64. B: register-direct coalesced fragment loads from L2.
// A: coalesced float4 row reads -> cvt f16 -> LDS dbuf (LDA=72 halves, 16B-aligned rows).
__global__ __launch_bounds__(512) void k_at(const float* __restrict__ xh,
    const float* __restrict__ xhpre, const _Float16* __restrict__ Bp,
    const float* __restrict__ bns, const float* __restrict__ bnb,
    float* __restrict__ a_t){
  constexpr int S = 4096, Dd = 256;
  constexpr int LDA = 72;
  const int bid = blockIdx.x;
  const int b  = bid >> 5;
  const int s0 = (bid & 31) * 128;
  const int tid = threadIdx.x;
  const int lane = tid & 63;
  const int w = tid >> 6;
  const int wm = w >> 2, wn = w & 3;
  const int kg = lane >> 4;      // 0..3
  const int lr = lane & 15;      // 0..15

  __shared__ _Float16 A[2][128 * LDA];
  __shared__ float bnsc[128], bnsh[128];
  __shared__ float red[4][128];

  if (tid < 128){ bnsc[tid] = bns[s0 + tid]; bnsh[tid] = bnb[s0 + tid]; }

  float xhv[4];
  #pragma unroll
  for (int nt = 0; nt < 4; ++nt) xhv[nt] = xh[b * 256 + wn * 64 + nt * 16 + lr];

  const float* Abase = xhpre + ((size_t)b * S + s0) * Dd;
  // staging map: inst i (0..3): row = w*16 + i*4 + rq, floats = k0*64 + lr*4 .. +4
  const int rq = lane >> 4;      // 0..3 (row-in-quad)

  // ---- prologue: stage K-step 0 ----
  #pragma unroll
  for (int i = 0; i < 4; ++i){
    int row = w * 16 + i * 4 + rq;
    float4 v = *reinterpret_cast<const float4*>(Abase + (size_t)row * Dd + lr * 4);
    union { _Float16 h[4]; uint2 u; } pk;
    pk.h[0]=(_Float16)v.x; pk.h[1]=(_Float16)v.y; pk.h[2]=(_Float16)v.z; pk.h[3]=(_Float16)v.w;
    *reinterpret_cast<uint2*>(&A[0][row * LDA + lr * 4]) = pk.u;
  }
  __syncthreads();

  f32x4 acc[4][4] = {};

  #pragma unroll
  for (int k0 = 0; k0 < 4; ++k0){
    // issue next-step A loads early (hide latency under MFMA)
    float4 nv[4];
    if (k0 < 3){
      #pragma unroll
      for (int i = 0; i < 4; ++i){
        int row = w * 16 + i * 4 + rq;
        nv[i] = *reinterpret_cast<const float4*>(Abase + (size_t)row * Dd + (k0 + 1) * 64 + lr * 4);
      }
    }

    const _Float16* Ar = &A[k0 & 1][0];
    #pragma unroll
    for (int kk = 0; kk < 2; ++kk){
      const int q = k0 * 2 + kk;
      half8 afr[4], bfr[4];
      #pragma unroll
      for (int nt = 0; nt < 4; ++nt)
        bfr[nt] = *reinterpret_cast<const half8*>(Bp + ((size_t)((q * 16 + wn * 4 + nt) * 64 + lane)) * 8);
      #pragma unroll
      for (int mt = 0; mt < 4; ++mt)
        afr[mt] = *reinterpret_cast<const half8*>(Ar + (wm * 64 + mt * 16 + lr) * LDA + kk * 32 + kg * 8);
      #pragma unroll
      for (int mt = 0; mt < 4; ++mt)
        #pragma unroll
        for (int nt = 0; nt < 4; ++nt)
          acc[mt][nt] = __builtin_amdgcn_mfma_f32_16x16x32_f16(afr[mt], bfr[nt], acc[mt][nt], 0, 0, 0);
    }

    if (k0 < 3){
      #pragma unroll
      for (int i = 0; i < 4; ++i){
        int row = w * 16 + i * 4 + rq;
        union { _Float16 h[4]; uint2 u; } pk;
        pk.h[0]=(_Float16)nv[i].x; pk.h[1]=(_Float16)nv[i].y;
        pk.h[2]=(_Float16)nv[i].z; pk.h[3]=(_Float16)nv[i].w;
        *reinterpret_cast<uint2*>(&A[(k0 + 1) & 1][row * LDA + lr * 4]) = pk.u;
      }
    }
    __syncthreads();
  }

  // epilogue: BN + tanh + dot(x_h); reduce 16 cols (lr) then 4 wn groups via LDS
  #pragma unroll
  for (int mt = 0; mt < 4; ++mt){
    #pragma unroll
    for (int r = 0; r < 4; ++r){
      int row = wm * 64 + mt * 16 + kg * 4 + r;   // C/D: col=lane&15, row=(lane>>4)*4+reg
      float sc = bnsc[row], sh = bnsh[row];
      float sum = 0.f;
      #pragma unroll
      for (int nt = 0; nt < 4; ++nt){
        float hv = fmaf(acc[mt][nt][r], sc, sh);
        sum = fmaf(tanh_fast(hv), xhv[nt], sum);
      }
      sum += __shfl_xor(sum, 1);
      sum += __shfl_xor(sum, 2);
      sum += __shfl_xor(sum, 4);
      sum += __shfl_xor(sum, 8);
      if (lr == 0) red[wn][row] = sum;
    }
  }
  __syncthreads();
  if (tid < 128){
    float v = red[0][tid] + red[1][tid] + red[2][tid] + red[3][tid];
    a_t[(size_t)b * S + s0 + tid] = v;
  }
}

// ---------------- softmax over s (4096) per b ----------------
__global__ __launch_bounds__(256) void k_softmax(const float* __restrict__ at, float* __restrict__ as_){
  int b = blockIdx.x, tid = threadIdx.x;
  int w = tid >> 6, lane = tid & 63;
  __shared__ float rm[4], rz[4];
  float v[16];
  float m = -1e30f;
  #pragma unroll
  for (int i = 0; i < 16; ++i){ v[i] = at[(size_t)b * 4096 + i * 256 + tid]; m = fmaxf(m, v[i]); }
  #pragma unroll
  for (int o = 1; o < 64; o <<= 1) m = fmaxf(m, __shfl_xor(m, o));
  if (lane == 0) rm[w] = m;
  __syncthreads();
  m = fmaxf(fmaxf(rm[0], rm[1]), fmaxf(rm[2], rm[3]));
  float e[16], z = 0.f;
  #pragma unroll
  for (int i = 0; i < 16; ++i){ e[i] = __expf(v[i] - m); z += e[i]; }
  #pragma unroll
  for (int o = 1; o < 64; o <<= 1) z += __shfl_xor(z, o);
  if (lane == 0) rz[w] = z;
  __syncthreads();
  z = rz[0] + rz[1] + rz[2] + rz[3];
  float inv = 1.0f / z;
  #pragma unroll
  for (int i = 0; i < 16; ++i) as_[(size_t)b * 4096 + i * 256 + tid] = e[i] * inv;
}

// ---------------- partial weighted sums over 128-s chunks, float4 lanes ----------------
__global__ __launch_bounds__(256) void k_wsum(const float* __restrict__ as_,
    const float* __restrict__ xp, float* __restrict__ partial){
  int bid = blockIdx.x;          // 64*32 = 2048
  int b = bid >> 5, c = bid & 31;
  int tid = threadIdx.x, w = tid >> 6, lane = tid & 63;
  __shared__ float av[128];
  __shared__ f32x4 red[4][64];
  if (tid < 128) av[tid] = as_[(size_t)b * 4096 + c * 128 + tid];
  __syncthreads();
  const float* x = xp + ((size_t)(b * 4096 + c * 128 + w * 32)) * 256 + lane * 4;
  f32x4 acc0 = {}, acc1 = {};
  #pragma unroll
  for (int s = 0; s < 32; s += 2){
    f32x4 v0 = *reinterpret_cast<const f32x4*>(x + (size_t)s * 256);
    f32x4 v1 = *reinterpret_cast<const f32x4*>(x + (size_t)(s + 1) * 256);
    float a0 = av[w * 32 + s], a1 = av[w * 32 + s + 1];
    acc0 += v0 * a0;
    acc1 += v1 * a1;
  }
  red[w][lane] = acc0 + acc1;
  __syncthreads();
  if (tid < 64){
    f32x4 r = red[0][tid] + red[1][tid] + red[2][tid] + red[3][tid];
    *reinterpret_cast<f32x4*>(partial + (size_t)bid * 256 + tid * 4) = r;
  }
}

// ---------------- final: out[b,d] = W2[d] * sum_c partial ----------------
__global__ __launch_bounds__(256) void k_out(const float* __restrict__ partial,
    const float* __restrict__ W2, float* __restrict__ out){
  int b = blockIdx.x, d = threadIdx.x;
  float s = 0.f;
  #pragma unroll
  for (int c = 0; c < 32; ++c) s += partial[(size_t)(b * 32 + c) * 256 + d];
  out[b * 256 + d] = s * W2[d];
}

extern "C" void kernel_launch(void* const* d_in, const int* in_sizes, int n_in,
                              void* d_out, int out_size, void* d_ws, size_t ws_size,
                              hipStream_t stream){
  const float* x_h    = (const float*)d_in[0];
  const float* x_hpre = (const float*)d_in[1];
  const float* W1     = (const float*)d_in[2];
  const float* W2     = (const float*)d_in[3];
  const float* gamma  = (const float*)d_in[4];
  const float* beta   = (const float*)d_in[5];
  const float* rmean  = (const float*)d_in[6];
  const float* rvar   = (const float*)d_in[7];
  float* out = (float*)d_out;

  char* ws = (char*)d_ws;
  _Float16* Bp = (_Float16*)(ws);           // 131072 B (fragment-ordered W1)
  float* bns  = (float*)(ws + 131072);      // 16 KB
  float* bnb  = (float*)(ws + 147456);      // 16 KB
  float* at   = (float*)(ws + 163840);      // 1 MB
  float* as_  = (float*)(ws + 1212416);     // 1 MB
  float* part = (float*)(ws + 2260992);     // 2 MB  (total ~4.2 MB)

  hipLaunchKernelGGL(k_prep,    dim3(256),  dim3(256), 0, stream, W1, gamma, beta, rmean, rvar, Bp, bns, bnb);
  hipLaunchKernelGGL(k_at,      dim3(2048), dim3(512), 0, stream, x_h, x_hpre, Bp, bns, bnb, at);
  hipLaunchKernelGGL(k_softmax, dim3(64),   dim3(256), 0, stream, at, as_);
  hipLaunchKernelGGL(k_wsum,    dim3(2048), dim3(256), 0, stream, as_, x_hpre, part);
  hipLaunchKernelGGL(k_out,     dim3(64),   dim3(256), 0, stream, part, W2, out);
}